// Round 14
// baseline (239.739 us; speedup 1.0000x reference)
//
#include <hip/hip_runtime.h>
#include <hip/hip_bf16.h>

// Problem constants
#define BB 64     // batch
#define NT 128    // text tokens
#define NV 256    // visual tokens
#define DD 512    // feature dim (bytes per row in fp8)
#define BKB 128   // K-chunk in bytes: one 16x16x128 f8f6f4 k-step
#define EPSF 1e-7f

typedef __attribute__((ext_vector_type(8))) int i32x8;
typedef __attribute__((ext_vector_type(4))) int i32x4;
typedef __attribute__((ext_vector_type(4))) float f32x4;

__device__ __forceinline__ void glds16(const uchar* g, uchar* l) {
    __builtin_amdgcn_global_load_lds(
        (const __attribute__((address_space(1))) unsigned int*)g,
        (__attribute__((address_space(3))) unsigned int*)l, 16, 0, 0);
}

// ---------------------------------------------------------------------------
// Kernel 1: L2-normalize rows, write fp8 e4m3 (OCP). Wave per row.
// Blocks 0-31 additionally zero the clip num/den partial arrays (8192 floats
// each) and reg_sum.
// ---------------------------------------------------------------------------
__global__ __launch_bounds__(256) void k_normalize(
    const float* __restrict__ tf, const float* __restrict__ vf,
    uchar* __restrict__ tn, uchar* __restrict__ vn,
    float* __restrict__ cs_num, float* __restrict__ cs_den,
    float* __restrict__ reg_sum) {
    if (blockIdx.x == 0 && threadIdx.x == 0) *reg_sum = 0.0f;
    if (blockIdx.x < 16) {
        int idx = blockIdx.x * 256 + threadIdx.x;   // 4096 pairs
        cs_num[idx] = 0.0f;
        cs_den[idx] = 0.0f;
    }
    const int w = threadIdx.x >> 6, l = threadIdx.x & 63;
    const int row = blockIdx.x * 4 + w;
    const float* src;
    uchar* dst;
    if (row < BB * NT) {
        src = tf + (size_t)row * DD;
        dst = tn + (size_t)row * DD;
    } else {
        int r = row - BB * NT;
        src = vf + (size_t)r * DD;
        dst = vn + (size_t)r * DD;
    }
    float4 x0 = ((const float4*)src)[l * 2];
    float4 x1 = ((const float4*)src)[l * 2 + 1];
    float ss = x0.x * x0.x + x0.y * x0.y + x0.z * x0.z + x0.w * x0.w
             + x1.x * x1.x + x1.y * x1.y + x1.z * x1.z + x1.w * x1.w;
    #pragma unroll
    for (int off = 32; off; off >>= 1) ss += __shfl_xor(ss, off, 64);
    float scale = 1.0f / fmaxf(sqrtf(ss), 1e-12f);
    int p0 = __builtin_amdgcn_cvt_pk_fp8_f32(x0.x * scale, x0.y * scale, 0, 0);
    p0 = __builtin_amdgcn_cvt_pk_fp8_f32(x0.z * scale, x0.w * scale, p0, 1);
    int p1 = __builtin_amdgcn_cvt_pk_fp8_f32(x1.x * scale, x1.y * scale, 0, 0);
    p1 = __builtin_amdgcn_cvt_pk_fp8_f32(x1.z * scale, x1.w * scale, p1, 1);
    ((uint2*)dst)[l] = make_uint2((unsigned)p0, (unsigned)p1);
}

// ---------------------------------------------------------------------------
// Kernel 2: ROUND-14 -- the ONE untested cell of the failure map. 4-wave
// block (256 thr), block tile 64x256 (i-half x full j), wave grid 1x4,
// wave tile 64x64 -> acc[4][4]: per-wave compute BIT-IDENTICAL to R8's
// proven spill-free shape; NO in-loop flush (R10/R11's spill factor).
// LDS = 8KB T single-buf + 2x32KB V dbuf + ~1KB = 73KB -> TWO blocks/CU
// (146KB LDS, 2 x 192 unified regs = 384 <= 512/SIMD). Same 8 waves/CU as
// R8 but two INDEPENDENT barrier domains: block B's MFMAs fill block A's
// vmcnt/barrier stalls (m114) -- the convoy idle neither schedule depth
// (R8) nor anything else touched. Row-split keeps row-max block-local;
// masked mean becomes atomicAdd num/den partials, divided in k_loss
// (algebraically exact). Staging offsets collapsed to one base (+s*16384;
// the rotation granule is s-invariant since 32 % 8 == 0) to keep register
// pressure at or below R8's. __launch_bounds__(256,2) = the proven
// 256-reg/wave budget.
// ---------------------------------------------------------------------------
__global__ __launch_bounds__(256, 2) void k_gemm(
    const uchar* __restrict__ tn, const uchar* __restrict__ vn,
    const int* __restrict__ mask,
    float* __restrict__ cs_num, float* __restrict__ cs_den,
    float* __restrict__ reg_sum) {
    __shared__ uchar sTT[64 * BKB];    // 8 KB (T single buffer)
    __shared__ uchar sV0[NV * BKB];    // 32 KB
    __shared__ uchar sV1[NV * BKB];    // 32 KB
    __shared__ float maxbuf[64][4];    // row-max partials per wave col-group
    __shared__ float redw[4];

    const int i = blockIdx.x >> 1, h = blockIdx.x & 1;   // text batch, row-half
    const int j = blockIdx.y;
    const int tid = threadIdx.x;
    const int l = tid & 63, w = tid >> 6;   // 4 waves
    const int wc = w;                        // wave grid 1x4: col group 0..3
    const int m15 = l & 15, q = l >> 4;

    const uchar* tbase = tn + ((size_t)i * NT + h * 64) * DD;
    const uchar* vbase = vn + (size_t)j * NV * DD;

    // Staging base: unit f = s*256+tid -> row r = s*32 + (tid>>3), phys
    // granule p = tid&7 holds logical g = (p - r)&7 = ((tid&7)-(tid>>3))&7
    // (s-invariant).  offset(s) = base + s*16384; LDS dest = s*4096 + tid*16.
    const int sbase = (tid >> 3) * DD + ((((tid & 7) - (tid >> 3)) & 7) * 16);
    const int ldst = tid * 16;

    // Fragment read addresses (rotation-mirrored, verified formulas).
    int a_b0[4], a_b1[4], b_b0[4], b_b1[4];
    #pragma unroll
    for (int rt = 0; rt < 4; ++rt) {
        int row = rt * 16 + m15;                 // T tile rows 0..63
        a_b0[rt] = row * BKB + (((2 * q + row) & 7) * 16);
        a_b1[rt] = row * BKB + (((2 * q + 1 + row) & 7) * 16);
    }
    #pragma unroll
    for (int ct = 0; ct < 4; ++ct) {
        int row = wc * 64 + ct * 16 + m15;       // V tile rows 0..255
        b_b0[ct] = row * BKB + (((2 * q + row) & 7) * 16);
        b_b1[ct] = row * BKB + (((2 * q + 1 + row) & 7) * 16);
    }

    f32x4 acc[4][4];
    #pragma unroll
    for (int rt = 0; rt < 4; ++rt)
        #pragma unroll
        for (int ct = 0; ct < 4; ++ct) acc[rt][ct] = (f32x4){0.f, 0.f, 0.f, 0.f};

    auto stageT = [&](int kk) {                  // 2 loads/thread (8 KB)
        #pragma unroll
        for (int s = 0; s < 2; ++s)
            glds16(tbase + sbase + s * 16384 + kk, sTT + s * 4096 + ldst);
    };
    auto stageV = [&](uchar* dV, int kk) {       // 8 loads/thread (32 KB)
        #pragma unroll
        for (int s = 0; s < 8; ++s)
            glds16(vbase + sbase + s * 16384 + kk, dV + s * 4096 + ldst);
    };
    auto compute = [&](const uchar* bV) {
        i32x8 bf[4];
        #pragma unroll
        for (int ct = 0; ct < 4; ++ct) {
            i32x4 lo = *(const i32x4*)(bV + b_b0[ct]);
            i32x4 hi = *(const i32x4*)(bV + b_b1[ct]);
            bf[ct] = (i32x8){lo.x, lo.y, lo.z, lo.w, hi.x, hi.y, hi.z, hi.w};
        }
        #pragma unroll
        for (int rt = 0; rt < 4; ++rt) {
            i32x4 lo = *(const i32x4*)(sTT + a_b0[rt]);
            i32x4 hi = *(const i32x4*)(sTT + a_b1[rt]);
            i32x8 a = (i32x8){lo.x, lo.y, lo.z, lo.w, hi.x, hi.y, hi.z, hi.w};
            #pragma unroll
            for (int ct = 0; ct < 4; ++ct)
                acc[rt][ct] = __builtin_amdgcn_mfma_scale_f32_16x16x128_f8f6f4(
                    a, bf[ct], acc[rt][ct],
                    0 /*A fmt=fp8*/, 0 /*B fmt=fp8*/,
                    0, 127 /*scaleA=1.0*/, 0, 127 /*scaleB=1.0*/);
        }
    };

    // --- schedule: T single-buf (re-staged after each compute), V 2-deep
    // dbuf with counted vmcnt. Per-wave FIFO at step k: outstanding =
    // {V(k):8, T(k):2 issued earlier...} -- issue order is
    // T(k),V(k+1) after compute(k-1), so before compute(k) the oldest 10
    // are {V(k),T(k)}; vmcnt(8) retires exactly them, leaving V(k+1).
    stageT(0);                 // 2
    stageV(sV0, 0);            // +8 = 10
    stageV(sV1, 1 * BKB);      // +8 = 18

    // k = 0
    asm volatile("s_waitcnt vmcnt(8)" ::: "memory");   // T0,V0 landed
    __builtin_amdgcn_s_barrier();
    asm volatile("" ::: "memory");
    compute(sV0);
    asm volatile("" ::: "memory");
    __builtin_amdgcn_s_barrier();                      // done reading sTT,sV0
    stageT(1 * BKB);
    stageV(sV0, 2 * BKB);

    // k = 1
    asm volatile("s_waitcnt vmcnt(8)" ::: "memory");   // V1,T1 landed
    __builtin_amdgcn_s_barrier();
    asm volatile("" ::: "memory");
    compute(sV1);
    asm volatile("" ::: "memory");
    __builtin_amdgcn_s_barrier();                      // done reading sTT,sV1
    stageT(2 * BKB);
    stageV(sV1, 3 * BKB);

    // k = 2
    asm volatile("s_waitcnt vmcnt(8)" ::: "memory");   // V2,T2 landed
    __builtin_amdgcn_s_barrier();
    asm volatile("" ::: "memory");
    compute(sV0);
    asm volatile("" ::: "memory");
    __builtin_amdgcn_s_barrier();                      // done reading sTT
    stageT(3 * BKB);

    // k = 3
    asm volatile("s_waitcnt vmcnt(0)" ::: "memory");   // V3,T3 landed
    __builtin_amdgcn_s_barrier();
    asm volatile("" ::: "memory");
    compute(sV1);

    // Epilogue 1: reg partial = sum of min(s,0)^2 over this lane's 64 values.
    float rp = 0.0f;
    #pragma unroll
    for (int rt = 0; rt < 4; ++rt)
        #pragma unroll
        for (int ct = 0; ct < 4; ++ct)
            #pragma unroll
            for (int r = 0; r < 4; ++r) {
                float m = fminf(acc[rt][ct][r], 0.0f);
                rp = fmaf(m, m, rp);
            }

    // Epilogue 2: row max. C/D layout: col = lane&15, row = q*4 + reg.
    #pragma unroll
    for (int rt = 0; rt < 4; ++rt)
        #pragma unroll
        for (int r = 0; r < 4; ++r) {
            float m = acc[rt][0][r];
            #pragma unroll
            for (int ct = 1; ct < 4; ++ct) m = fmaxf(m, acc[rt][ct][r]);
            #pragma unroll
            for (int msk = 1; msk < 16; msk <<= 1)
                m = fmaxf(m, __shfl_xor(m, msk, 64));
            if (m15 == 0)
                maxbuf[rt * 16 + q * 4 + r][wc] = m;
        }

    #pragma unroll
    for (int off = 32; off; off >>= 1) rp += __shfl_down(rp, off, 64);
    if (l == 0) redw[w] = rp;
    __syncthreads();

    // Masked-mean PARTIALS over this block's 64 text rows (wave 0 only).
    if (tid < 64) {
        float rm = fmaxf(fmaxf(maxbuf[tid][0], maxbuf[tid][1]),
                         fmaxf(maxbuf[tid][2], maxbuf[tid][3]));
        float mf = (float)mask[i * NT + h * 64 + tid];
        float v = rm * mf;
        #pragma unroll
        for (int off = 32; off; off >>= 1) {
            v += __shfl_down(v, off, 64);
            mf += __shfl_down(mf, off, 64);
        }
        if (tid == 0) {
            atomicAdd(cs_num + i * BB + j, v);
            atomicAdd(cs_den + i * BB + j, mf);
            atomicAdd(reg_sum, redw[0] + redw[1] + redw[2] + redw[3]);
        }
    }
}

// ---------------------------------------------------------------------------
// Kernel 3: final scalar loss. Single block, 256 threads. clip = num/den.
// ---------------------------------------------------------------------------
__global__ __launch_bounds__(256) void k_loss(
    const float* __restrict__ cs_num, const float* __restrict__ cs_den,
    const float* __restrict__ reg_sum, float* __restrict__ out) {
    __shared__ float sc[BB][BB + 1];
    __shared__ float lrow[BB], lcol[BB];
    int tid = threadIdx.x;
    for (int idx = tid; idx < BB * BB; idx += 256)
        sc[idx / BB][idx % BB] = cs_num[idx] / fmaxf(cs_den[idx], EPSF);
    __syncthreads();
    if (tid < BB) {
        int i = tid;
        float m = sc[i][0];
        #pragma unroll
        for (int j = 1; j < BB; ++j) m = fmaxf(m, sc[i][j]);
        float s = 0.0f;
        #pragma unroll
        for (int j = 0; j < BB; ++j) s += expf(sc[i][j] - m);
        lrow[i] = m + logf(s) - sc[i][i];
    } else if (tid < 2 * BB) {
        int i = tid - BB;
        float m = sc[0][i];
        #pragma unroll
        for (int j = 1; j < BB; ++j) m = fmaxf(m, sc[j][i]);
        float s = 0.0f;
        #pragma unroll
        for (int j = 0; j < BB; ++j) s += expf(sc[j][i] - m);
        lcol[i] = m + logf(s) - sc[i][i];
    }
    __syncthreads();
    if (tid == 0) {
        float tot = 0.0f;
        for (int i = 0; i < BB; ++i) tot += lrow[i] + lcol[i];
        float contrastive = tot / (2.0f * BB);
        double denom = (double)BB * BB * NT * NV;  // 134217728
        float reg = 0.15f * (float)((double)reg_sum[0] / denom);
        out[0] = contrastive + reg;
    }
}

// ---------------------------------------------------------------------------
extern "C" void kernel_launch(void* const* d_in, const int* in_sizes, int n_in,
                              void* d_out, int out_size, void* d_ws, size_t ws_size,
                              hipStream_t stream) {
    const float* tf = (const float*)d_in[0];   // (B, NT, D) fp32
    const float* vf = (const float*)d_in[1];   // (B, NV, D) fp32
    const int* mask = (const int*)d_in[2];     // (B, NT) int32
    float* out = (float*)d_out;                // scalar fp32

    char* ws = (char*)d_ws;
    size_t tn_bytes = (size_t)BB * NT * DD;              // 4 MB fp8
    size_t vn_bytes = (size_t)BB * NV * DD;              // 8 MB fp8
    size_t cs_bytes = (size_t)BB * BB * sizeof(float);   // 16 KB

    uchar* tn = (uchar*)ws;
    uchar* vn = (uchar*)(ws + tn_bytes);
    float* cs_num = (float*)(ws + tn_bytes + vn_bytes);
    float* cs_den = (float*)(ws + tn_bytes + vn_bytes + cs_bytes);
    float* reg_sum = (float*)(ws + tn_bytes + vn_bytes + 2 * cs_bytes);

    k_normalize<<<(BB * NT + BB * NV) / 4, 256, 0, stream>>>(
        tf, vf, tn, vn, cs_num, cs_den, reg_sum);
    // 8192 blocks: 128 (i x row-half) x 64 j.
    k_gemm<<<dim3(BB * 2, BB), 256, 0, stream>>>(
        tn, vn, mask, cs_num, cs_den, reg_sum);
    k_loss<<<1, 256, 0, stream>>>(cs_num, cs_den, reg_sum, out);
}

// Round 15
// 230.423 us; speedup vs baseline: 1.0404x; 1.0404x over previous
//
#include <hip/hip_runtime.h>
#include <hip/hip_bf16.h>

// Problem constants
#define BB 64     // batch
#define NT 128    // text tokens
#define NV 256    // visual tokens
#define DD 512    // feature dim (bytes per row in fp8)
#define BKB 128   // K-chunk in bytes: one 16x16x128 f8f6f4 k-step
#define EPSF 1e-7f

typedef __attribute__((ext_vector_type(8))) int i32x8;
typedef __attribute__((ext_vector_type(4))) int i32x4;
typedef __attribute__((ext_vector_type(4))) float f32x4;

__device__ __forceinline__ void glds16(const uchar* g, uchar* l) {
    __builtin_amdgcn_global_load_lds(
        (const __attribute__((address_space(1))) unsigned int*)g,
        (__attribute__((address_space(3))) unsigned int*)l, 16, 0, 0);
}

// ---------------------------------------------------------------------------
// Kernel 1: L2-normalize rows, write fp8 e4m3 (OCP). Wave per row.
// ---------------------------------------------------------------------------
__global__ __launch_bounds__(256) void k_normalize(
    const float* __restrict__ tf, const float* __restrict__ vf,
    uchar* __restrict__ tn, uchar* __restrict__ vn,
    float* __restrict__ reg_sum) {
    if (blockIdx.x == 0 && threadIdx.x == 0) *reg_sum = 0.0f;
    const int w = threadIdx.x >> 6, l = threadIdx.x & 63;
    const int row = blockIdx.x * 4 + w;
    const float* src;
    uchar* dst;
    if (row < BB * NT) {
        src = tf + (size_t)row * DD;
        dst = tn + (size_t)row * DD;
    } else {
        int r = row - BB * NT;
        src = vf + (size_t)r * DD;
        dst = vn + (size_t)r * DD;
    }
    float4 x0 = ((const float4*)src)[l * 2];
    float4 x1 = ((const float4*)src)[l * 2 + 1];
    float ss = x0.x * x0.x + x0.y * x0.y + x0.z * x0.z + x0.w * x0.w
             + x1.x * x1.x + x1.y * x1.y + x1.z * x1.z + x1.w * x1.w;
    #pragma unroll
    for (int off = 32; off; off >>= 1) ss += __shfl_xor(ss, off, 64);
    float scale = 1.0f / fmaxf(sqrtf(ss), 1e-12f);
    int p0 = __builtin_amdgcn_cvt_pk_fp8_f32(x0.x * scale, x0.y * scale, 0, 0);
    p0 = __builtin_amdgcn_cvt_pk_fp8_f32(x0.z * scale, x0.w * scale, p0, 1);
    int p1 = __builtin_amdgcn_cvt_pk_fp8_f32(x1.x * scale, x1.y * scale, 0, 0);
    p1 = __builtin_amdgcn_cvt_pk_fp8_f32(x1.z * scale, x1.w * scale, p1, 1);
    ((uint2*)dst)[l] = make_uint2((unsigned)p0, (unsigned)p1);
}

// ---------------------------------------------------------------------------
// Kernel 2: the measured-optimal structure (best total 230.35us, k_gemm
// ~149us, absmax 0.0; re-verified twice). 128x256 tile per (i,j) pair,
// T+V LDS DMA double buffer with rotation swizzle, acc[4][4] (VGPR=128 --
// the ONLY spill-free register shape), 2-deep prefetch with counted vmcnt,
// post-loop epilogue.
// Session map (rounds 2-14, all measured): register-wall pinned. 192
// unified regs/wave => 2 waves/SIMD => 8 waves/CU. Nulls/failures:
// deeper schedules (null), bigger tiles (spill), more waves via bounds
// (ignored/spill), 4-wave blocks w/ in-loop flush (spill), 4-wave blocks
// w/ clean epilogue (2 blocks/CU co-resident but null MfmaUtil + 2x V
// staging => -9%), multi-j (spill), direct-global operands (-47%), fused
// loss tail (spill, -47%). The residual idle (MfmaUtil 18%, HBM 4%) is
// dependency-chain latency at the register-file-capped concurrency --
// not a saturated pipe, but every mapped escape is measured worse.
// ---------------------------------------------------------------------------
__global__ __launch_bounds__(512, 2) void k_gemm(
    const uchar* __restrict__ tn, const uchar* __restrict__ vn,
    const int* __restrict__ mask,
    float* __restrict__ clip_sims, float* __restrict__ reg_sum) {
    __shared__ uchar sT0[NT * BKB];   // 16 KB
    __shared__ uchar sT1[NT * BKB];   // 16 KB
    __shared__ uchar sV0[NV * BKB];   // 32 KB
    __shared__ uchar sV1[NV * BKB];   // 32 KB
    __shared__ float maxbuf[NT][4];   // row-max partials per wave col-group
    __shared__ float redw[8];
    __shared__ float c0[2], c1[2];

    const int i = blockIdx.x, j = blockIdx.y;
    const int tid = threadIdx.x;
    const int l = tid & 63, w = tid >> 6;
    const int wr = w >> 2, wc = w & 3;      // wave row-group (0..1), col-group (0..3)
    const int m15 = l & 15, q = l >> 4;

    const uchar* tbase = tn + (size_t)i * NT * DD;
    const uchar* vbase = vn + (size_t)j * NV * DD;

    // Staging: 16B unit f -> row r = f>>3, phys granule p = f&7 holds
    // logical granule g = (p - r) & 7.  src = r*DD + kk + g*16.
    int t_off[2], v_off[4];
    #pragma unroll
    for (int s = 0; s < 2; ++s) {
        int f = s * 512 + tid;
        int r = f >> 3, p = f & 7, g = (p - r) & 7;
        t_off[s] = r * DD + g * 16;
    }
    #pragma unroll
    for (int s = 0; s < 4; ++s) {
        int f = s * 512 + tid;
        int r = f >> 3, p = f & 7, g = (p - r) & 7;
        v_off[s] = r * DD + g * 16;
    }

    // Fragment read addresses: lane holds k = q*32..q*32+31 of its row,
    // logical granules 2q, 2q+1 -> phys (2q+row)&7, (2q+1+row)&7.
    int a_b0[4], a_b1[4], b_b0[4], b_b1[4];
    #pragma unroll
    for (int rt = 0; rt < 4; ++rt) {
        int row = wr * 64 + rt * 16 + m15;
        a_b0[rt] = row * BKB + (((2 * q + row) & 7) * 16);
        a_b1[rt] = row * BKB + (((2 * q + 1 + row) & 7) * 16);
    }
    #pragma unroll
    for (int ct = 0; ct < 4; ++ct) {
        int row = wc * 64 + ct * 16 + m15;
        b_b0[ct] = row * BKB + (((2 * q + row) & 7) * 16);
        b_b1[ct] = row * BKB + (((2 * q + 1 + row) & 7) * 16);
    }

    f32x4 acc[4][4];
    #pragma unroll
    for (int rt = 0; rt < 4; ++rt)
        #pragma unroll
        for (int ct = 0; ct < 4; ++ct) acc[rt][ct] = (f32x4){0.f, 0.f, 0.f, 0.f};

    auto stage = [&](uchar* dT, uchar* dV, int kk) {
        #pragma unroll
        for (int s = 0; s < 2; ++s)
            glds16(tbase + t_off[s] + kk, dT + (s * 512 + tid) * 16);
        #pragma unroll
        for (int s = 0; s < 4; ++s)
            glds16(vbase + v_off[s] + kk, dV + (s * 512 + tid) * 16);
    };
    auto compute = [&](const uchar* bT, const uchar* bV) {
        i32x8 bf[4];
        #pragma unroll
        for (int ct = 0; ct < 4; ++ct) {
            i32x4 lo = *(const i32x4*)(bV + b_b0[ct]);
            i32x4 hi = *(const i32x4*)(bV + b_b1[ct]);
            bf[ct] = (i32x8){lo.x, lo.y, lo.z, lo.w, hi.x, hi.y, hi.z, hi.w};
        }
        #pragma unroll
        for (int rt = 0; rt < 4; ++rt) {
            i32x4 lo = *(const i32x4*)(bT + a_b0[rt]);
            i32x4 hi = *(const i32x4*)(bT + a_b1[rt]);
            i32x8 a = (i32x8){lo.x, lo.y, lo.z, lo.w, hi.x, hi.y, hi.z, hi.w};
            #pragma unroll
            for (int ct = 0; ct < 4; ++ct)
                acc[rt][ct] = __builtin_amdgcn_mfma_scale_f32_16x16x128_f8f6f4(
                    a, bf[ct], acc[rt][ct],
                    0 /*A fmt=fp8*/, 0 /*B fmt=fp8*/,
                    0, 127 /*scaleA=1.0*/, 0, 127 /*scaleB=1.0*/);
        }
    };

    // --- 2-deep pipelined schedule with counted vmcnt ---------------------
    // Outstanding DMA per wave is always {oldest tile: 6, newest tile: 6}.
    stage(sT0, sV0, 0);          // tile 0 -> 6 outstanding
    stage(sT1, sV1, 1 * BKB);    // tile 1 -> 12 outstanding

    // ks = 0
    asm volatile("s_waitcnt vmcnt(6)" ::: "memory");   // tile 0 landed
    __builtin_amdgcn_s_barrier();
    asm volatile("" ::: "memory");
    compute(sT0, sV0);
    asm volatile("" ::: "memory");
    __builtin_amdgcn_s_barrier();                      // all done reading buf0
    stage(sT0, sV0, 2 * BKB);    // tile 2 -> 12 outstanding

    // ks = 1
    asm volatile("s_waitcnt vmcnt(6)" ::: "memory");   // tile 1 landed
    __builtin_amdgcn_s_barrier();
    asm volatile("" ::: "memory");
    compute(sT1, sV1);
    asm volatile("" ::: "memory");
    __builtin_amdgcn_s_barrier();                      // all done reading buf1
    stage(sT1, sV1, 3 * BKB);    // tile 3 -> 12 outstanding

    // ks = 2
    asm volatile("s_waitcnt vmcnt(6)" ::: "memory");   // tile 2 landed
    __builtin_amdgcn_s_barrier();
    asm volatile("" ::: "memory");
    compute(sT0, sV0);
    asm volatile("" ::: "memory");
    __builtin_amdgcn_s_barrier();

    // ks = 3
    asm volatile("s_waitcnt vmcnt(0)" ::: "memory");   // tile 3 landed
    __builtin_amdgcn_s_barrier();
    asm volatile("" ::: "memory");
    compute(sT1, sV1);

    // Epilogue 1: reg partial = sum of min(s,0)^2 over this lane's 64 values.
    float rp = 0.0f;
    #pragma unroll
    for (int rt = 0; rt < 4; ++rt)
        #pragma unroll
        for (int ct = 0; ct < 4; ++ct)
            #pragma unroll
            for (int r = 0; r < 4; ++r) {
                float m = fminf(acc[rt][ct][r], 0.0f);
                rp = fmaf(m, m, rp);
            }

    // Epilogue 2: row max. C/D layout: col = lane&15, row = q*4 + reg.
    #pragma unroll
    for (int rt = 0; rt < 4; ++rt)
        #pragma unroll
        for (int r = 0; r < 4; ++r) {
            float m = acc[rt][0][r];
            #pragma unroll
            for (int ct = 1; ct < 4; ++ct) m = fmaxf(m, acc[rt][ct][r]);
            #pragma unroll
            for (int msk = 1; msk < 16; msk <<= 1)
                m = fmaxf(m, __shfl_xor(m, msk, 64));
            if (m15 == 0)
                maxbuf[wr * 64 + rt * 16 + q * 4 + r][wc] = m;
        }

    #pragma unroll
    for (int off = 32; off; off >>= 1) rp += __shfl_down(rp, off, 64);
    if (l == 0) redw[w] = rp;
    __syncthreads();

    // Fused clip: masked mean of row maxes over the 128 text tokens.
    if (tid < NT) {
        float rm = fmaxf(fmaxf(maxbuf[tid][0], maxbuf[tid][1]),
                         fmaxf(maxbuf[tid][2], maxbuf[tid][3]));
        float mf = (float)mask[i * NT + tid];
        float v = rm * mf;
        #pragma unroll
        for (int off = 32; off; off >>= 1) {
            v += __shfl_down(v, off, 64);
            mf += __shfl_down(mf, off, 64);
        }
        if (l == 0) { c0[w] = v; c1[w] = mf; }
    }
    __syncthreads();
    if (tid == 0) {
        clip_sims[i * BB + j] = (c0[0] + c0[1]) / fmaxf(c1[0] + c1[1], EPSF);
        float s = 0.0f;
        #pragma unroll
        for (int x = 0; x < 8; ++x) s += redw[x];
        atomicAdd(reg_sum, s);
    }
}

// ---------------------------------------------------------------------------
// Kernel 3: final scalar loss. Single block, 256 threads.
// ---------------------------------------------------------------------------
__global__ __launch_bounds__(256) void k_loss(
    const float* __restrict__ clip_sims, const float* __restrict__ reg_sum,
    float* __restrict__ out) {
    __shared__ float sc[BB][BB + 1];
    __shared__ float lrow[BB], lcol[BB];
    int tid = threadIdx.x;
    for (int idx = tid; idx < BB * BB; idx += 256)
        sc[idx / BB][idx % BB] = clip_sims[idx];
    __syncthreads();
    if (tid < BB) {
        int i = tid;
        float m = sc[i][0];
        #pragma unroll
        for (int j = 1; j < BB; ++j) m = fmaxf(m, sc[i][j]);
        float s = 0.0f;
        #pragma unroll
        for (int j = 0; j < BB; ++j) s += expf(sc[i][j] - m);
        lrow[i] = m + logf(s) - sc[i][i];
    } else if (tid < 2 * BB) {
        int i = tid - BB;
        float m = sc[0][i];
        #pragma unroll
        for (int j = 1; j < BB; ++j) m = fmaxf(m, sc[j][i]);
        float s = 0.0f;
        #pragma unroll
        for (int j = 0; j < BB; ++j) s += expf(sc[j][i] - m);
        lcol[i] = m + logf(s) - sc[i][i];
    }
    __syncthreads();
    if (tid == 0) {
        float tot = 0.0f;
        for (int i = 0; i < BB; ++i) tot += lrow[i] + lcol[i];
        float contrastive = tot / (2.0f * BB);
        double denom = (double)BB * BB * NT * NV;  // 134217728
        float reg = 0.15f * (float)((double)reg_sum[0] / denom);
        out[0] = contrastive + reg;
    }
}

// ---------------------------------------------------------------------------
extern "C" void kernel_launch(void* const* d_in, const int* in_sizes, int n_in,
                              void* d_out, int out_size, void* d_ws, size_t ws_size,
                              hipStream_t stream) {
    const float* tf = (const float*)d_in[0];   // (B, NT, D) fp32
    const float* vf = (const float*)d_in[1];   // (B, NV, D) fp32
    const int* mask = (const int*)d_in[2];     // (B, NT) int32
    float* out = (float*)d_out;                // scalar fp32

    char* ws = (char*)d_ws;
    size_t tn_bytes = (size_t)BB * NT * DD;              // 4 MB fp8
    size_t vn_bytes = (size_t)BB * NV * DD;              // 8 MB fp8
    size_t cs_bytes = (size_t)BB * BB * sizeof(float);   // 16 KB

    uchar* tn = (uchar*)ws;
    uchar* vn = (uchar*)(ws + tn_bytes);
    float* clip_sims = (float*)(ws + tn_bytes + vn_bytes);
    float* reg_sum = (float*)(ws + tn_bytes + vn_bytes + cs_bytes);

    k_normalize<<<(BB * NT + BB * NV) / 4, 256, 0, stream>>>(tf, vf, tn, vn, reg_sum);
    k_gemm<<<dim3(BB, BB), 512, 0, stream>>>(tn, vn, mask, clip_sims, reg_sum);
    k_loss<<<1, 256, 0, stream>>>(clip_sims, reg_sum, out);
}